// Round 1
// baseline (900.379 us; speedup 1.0000x reference)
//
#include <hip/hip_runtime.h>
#include <math.h>

#define N_NODESC 100000
#define N_EDGESC 1600000
#define DIMC 128
#define EPSV 1e-12f

// ---------------- per-node pretransform: b_tan = logmap0(b_emb), s_nrm = l2_normalize(s_emb)
__global__ void pretransform_k(const float* __restrict__ b_emb,
                               const float* __restrict__ s_emb,
                               float* __restrict__ b_tan,
                               float* __restrict__ s_nrm) {
    int wave = (blockIdx.x * blockDim.x + threadIdx.x) >> 6;
    int lane = threadIdx.x & 63;
    if (wave >= N_NODESC) return;
    const float2* bp = (const float2*)(b_emb + (size_t)wave * DIMC);
    const float2* sp = (const float2*)(s_emb + (size_t)wave * DIMC);
    float2 bv = bp[lane];
    float2 sv = sp[lane];
    float bss = bv.x * bv.x + bv.y * bv.y;
    float sss = sv.x * sv.x + sv.y * sv.y;
    #pragma unroll
    for (int m = 1; m < 64; m <<= 1) {
        bss += __shfl_xor(bss, m, 64);
        sss += __shfl_xor(sss, m, 64);
    }
    float bn   = sqrtf(bss);
    float bns  = fmaxf(bn, EPSV);
    float bcl  = fminf(fmaxf(bns, EPSV), 1.0f - 1e-5f);
    float bsc  = atanhf(bcl) / bns;
    float sn   = sqrtf(sss);
    float ssc  = 1.0f / fmaxf(sn, EPSV);
    float2* bo = (float2*)(b_tan + (size_t)wave * DIMC);
    float2* so = (float2*)(s_nrm + (size_t)wave * DIMC);
    bo[lane] = make_float2(bv.x * bsc, bv.y * bsc);
    so[lane] = make_float2(sv.x * ssc, sv.y * ssc);
}

// ---------------- CSR build: histogram, two-level scan, fill
__global__ void hist_k(const int* __restrict__ dst, int* __restrict__ deg) {
    int e = blockIdx.x * 256 + threadIdx.x;
    if (e < N_EDGESC) atomicAdd(&deg[dst[e]], 1);
}

__global__ void scan1_k(const int* __restrict__ deg, int* __restrict__ scanned,
                        int* __restrict__ partials) {
    __shared__ int s[256];
    int t = threadIdx.x;
    int g = blockIdx.x * 256 + t;
    int v = (g < N_NODESC) ? deg[g] : 0;
    s[t] = v;
    __syncthreads();
    for (int off = 1; off < 256; off <<= 1) {
        int x = (t >= off) ? s[t - off] : 0;
        __syncthreads();
        s[t] += x;
        __syncthreads();
    }
    if (g < N_NODESC) scanned[g] = s[t];
    if (t == 255) partials[blockIdx.x] = s[255];
}

__global__ void scan2_k(const int* __restrict__ partials, int* __restrict__ blockoff, int nb) {
    __shared__ int s[512];
    int t = threadIdx.x;
    int v = (t < nb) ? partials[t] : 0;
    s[t] = v;
    __syncthreads();
    for (int off = 1; off < 512; off <<= 1) {
        int x = (t >= off) ? s[t - off] : 0;
        __syncthreads();
        s[t] += x;
        __syncthreads();
    }
    if (t < nb) blockoff[t] = s[t] - v;  // exclusive
}

__global__ void scan3_k(const int* __restrict__ scanned, const int* __restrict__ blockoff,
                        int* __restrict__ offs) {
    int g = blockIdx.x * 256 + threadIdx.x;
    if (g < N_NODESC) offs[g + 1] = scanned[g] + blockoff[blockIdx.x];
    if (g == 0) offs[0] = 0;
}

__global__ void fill_k(const int* __restrict__ src, const int* __restrict__ dst,
                       const int* __restrict__ offs, int* __restrict__ cursor,
                       int* __restrict__ esrc) {
    int e = blockIdx.x * 256 + threadIdx.x;
    if (e < N_EDGESC) {
        int d = dst[e];
        int pos = offs[d] + atomicAdd(&cursor[d], 1);
        esrc[pos] = src[e];
    }
}

// ---------------- aggregation: one wave per node, gather over sorted incoming edges.
// Writes the three per-channel means directly into d_out (later transformed in-place).
__global__ void aggregate_k(const float* __restrict__ e_emb,
                            const float* __restrict__ b_tan,
                            const float* __restrict__ s_nrm,
                            const int* __restrict__ offs,
                            const int* __restrict__ esrc,
                            float* __restrict__ out) {
    int wave = (blockIdx.x * blockDim.x + threadIdx.x) >> 6;
    int lane = threadIdx.x & 63;
    if (wave >= N_NODESC) return;
    int beg = offs[wave], end = offs[wave + 1];
    float2 ae = make_float2(0.f, 0.f), ab = make_float2(0.f, 0.f), as = make_float2(0.f, 0.f);
    for (int j = beg; j < end; ++j) {
        int s = esrc[j];
        float2 ve = ((const float2*)(e_emb + (size_t)s * DIMC))[lane];
        float2 vb = ((const float2*)(b_tan + (size_t)s * DIMC))[lane];
        float2 vs = ((const float2*)(s_nrm + (size_t)s * DIMC))[lane];
        ae.x += ve.x; ae.y += ve.y;
        ab.x += vb.x; ab.y += vb.y;
        as.x += vs.x; as.y += vs.y;
    }
    int deg = end - beg;
    float inv = (deg > 0) ? 1.0f / (float)deg : 0.0f;
    ((float2*)(out + (size_t)wave * DIMC))[lane]                      = make_float2(ae.x * inv, ae.y * inv);
    ((float2*)(out + (size_t)(N_NODESC + wave) * DIMC))[lane]          = make_float2(ab.x * inv, ab.y * inv);
    ((float2*)(out + (size_t)(2 * (size_t)N_NODESC + wave) * DIMC))[lane] = make_float2(as.x * inv, as.y * inv);
}

// ---------------- fused GEMM (out = act(A @ W^T + bias)) in-place on d_out.
// Tile: 64 rows x 128 cols, 256 threads, each thread 8x4 accumulators.
// K split into two halves of 64 to keep LDS (At + Wt) under 64 KB.
__global__ __launch_bounds__(256) void gemm_act_k(
    float* __restrict__ out,
    const float* __restrict__ W_e, const float* __restrict__ b_e,
    const float* __restrict__ W_b, const float* __restrict__ b_b,
    const float* __restrict__ W_s, const float* __restrict__ b_s,
    const int* __restrict__ deg) {
    __shared__ float At[64][68];   // At[k][m], 17.4 KB
    __shared__ float Wt[64][132];  // Wt[k][j], 33.8 KB
    int c = blockIdx.y;
    const float* W    = (c == 0) ? W_e : (c == 1) ? W_b : W_s;
    const float* bias = (c == 0) ? b_e : (c == 1) ? b_b : b_s;
    float* A = out + (size_t)c * N_NODESC * DIMC;
    int m0 = blockIdx.x * 64;
    int tid = threadIdx.x;
    int tx = tid & 31;   // j-group: cols tx*4 .. tx*4+3
    int ty = tid >> 5;   // m-group: rows ty*8 .. ty*8+7
    float acc[8][4] = {};

    for (int h = 0; h < 2; ++h) {
        __syncthreads();
        // stage A^T half
        {
            int m = tid & 63, kq = tid >> 6;  // kq in 0..3
            int row = m0 + m;
            #pragma unroll
            for (int r = 0; r < 4; ++r) {
                int k0 = kq * 16 + r * 4;
                float4 v = make_float4(0.f, 0.f, 0.f, 0.f);
                if (row < N_NODESC)
                    v = *(const float4*)(A + (size_t)row * DIMC + h * 64 + k0);
                At[k0 + 0][m] = v.x; At[k0 + 1][m] = v.y;
                At[k0 + 2][m] = v.z; At[k0 + 3][m] = v.w;
            }
        }
        // stage W^T half
        {
            int j = tid & 127, kh = tid >> 7;  // kh in 0..1
            #pragma unroll
            for (int r = 0; r < 8; ++r) {
                int k0 = kh * 32 + r * 4;
                float4 v = *(const float4*)(W + (size_t)j * DIMC + h * 64 + k0);
                Wt[k0 + 0][j] = v.x; Wt[k0 + 1][j] = v.y;
                Wt[k0 + 2][j] = v.z; Wt[k0 + 3][j] = v.w;
            }
        }
        __syncthreads();
        #pragma unroll 4
        for (int k = 0; k < 64; ++k) {
            float4 w  = *(const float4*)&Wt[k][tx * 4];
            float4 a0 = *(const float4*)&At[k][ty * 8];
            float4 a1 = *(const float4*)&At[k][ty * 8 + 4];
            float am[8] = {a0.x, a0.y, a0.z, a0.w, a1.x, a1.y, a1.z, a1.w};
            #pragma unroll
            for (int r = 0; r < 8; ++r) {
                acc[r][0] += am[r] * w.x;
                acc[r][1] += am[r] * w.y;
                acc[r][2] += am[r] * w.z;
                acc[r][3] += am[r] * w.w;
            }
        }
    }

    float4 bv = *(const float4*)(bias + tx * 4);
    #pragma unroll
    for (int r = 0; r < 8; ++r) {
        int m = ty * 8 + r;
        int row = m0 + m;
        if (row >= N_NODESC) continue;  // uniform across the 32-lane tx group (row depends on ty,r only)
        float z0 = acc[r][0] + bv.x;
        float z1 = acc[r][1] + bv.y;
        float z2 = acc[r][2] + bv.z;
        float z3 = acc[r][3] + bv.w;
        float4 o;
        if (c == 0) {
            o.x = (z0 >= 0.f) ? z0 : 0.2f * z0;
            o.y = (z1 >= 0.f) ? z1 : 0.2f * z1;
            o.z = (z2 >= 0.f) ? z2 : 0.2f * z2;
            o.w = (z3 >= 0.f) ? z3 : 0.2f * z3;
        } else {
            float ss = z0 * z0 + z1 * z1 + z2 * z2 + z3 * z3;
            #pragma unroll
            for (int mm = 1; mm < 32; mm <<= 1) ss += __shfl_xor(ss, mm, 64);
            float n = sqrtf(ss);
            float scale;
            if (c == 1) {
                float nsafe = fmaxf(n, EPSV);
                scale = tanhf(nsafe) / nsafe;       // expmap0
            } else {
                scale = 1.0f / fmaxf(n, EPSV);      // l2_normalize
            }
            if (deg[row] <= 0) scale = 0.0f;        // mean_aggregate ran last in b/s paths
            o = make_float4(z0 * scale, z1 * scale, z2 * scale, z3 * scale);
        }
        *(float4*)(A + (size_t)row * DIMC + tx * 4) = o;
    }
}

extern "C" void kernel_launch(void* const* d_in, const int* in_sizes, int n_in,
                              void* d_out, int out_size, void* d_ws, size_t ws_size,
                              hipStream_t stream) {
    const float* e_emb = (const float*)d_in[0];
    const float* b_emb = (const float*)d_in[1];
    const float* s_emb = (const float*)d_in[2];
    const float* W_e   = (const float*)d_in[3];
    const float* b_e   = (const float*)d_in[4];
    const float* W_b   = (const float*)d_in[5];
    const float* b_b   = (const float*)d_in[6];
    const float* W_s   = (const float*)d_in[7];
    const float* b_s   = (const float*)d_in[8];
    const int*   src   = (const int*)d_in[9];
    const int*   dst   = (const int*)d_in[10];
    float* out = (float*)d_out;

    // workspace layout
    char* w = (char*)d_ws;
    float* b_tan = (float*)w;  w += (size_t)N_NODESC * DIMC * sizeof(float);
    float* s_nrm = (float*)w;  w += (size_t)N_NODESC * DIMC * sizeof(float);
    int* deg      = (int*)w;   w += (size_t)N_NODESC * sizeof(int);
    int* cursor   = (int*)w;   w += (size_t)N_NODESC * sizeof(int);
    int* scanned  = (int*)w;   w += (size_t)N_NODESC * sizeof(int);
    int* partials = (int*)w;   w += 512 * sizeof(int);
    int* blockoff = (int*)w;   w += 512 * sizeof(int);
    int* offs     = (int*)w;   w += (size_t)(N_NODESC + 1) * sizeof(int);
    w = (char*)(((uintptr_t)w + 255) & ~(uintptr_t)255);
    int* esrc     = (int*)w;   w += (size_t)N_EDGESC * sizeof(int);

    const int nbScan  = (N_NODESC + 255) / 256;   // 391
    const int nbEdge  = (N_EDGESC + 255) / 256;   // 6250
    const int nbNode4 = (N_NODESC + 3) / 4;       // 25000 (one wave per node, 4 waves/block)
    const int nbTile  = (N_NODESC + 63) / 64;     // 1563

    // deg and cursor are adjacent -> one memset
    hipMemsetAsync(deg, 0, (size_t)2 * N_NODESC * sizeof(int), stream);

    pretransform_k<<<nbNode4, 256, 0, stream>>>(b_emb, s_emb, b_tan, s_nrm);
    hist_k<<<nbEdge, 256, 0, stream>>>(dst, deg);
    scan1_k<<<nbScan, 256, 0, stream>>>(deg, scanned, partials);
    scan2_k<<<1, 512, 0, stream>>>(partials, blockoff, nbScan);
    scan3_k<<<nbScan, 256, 0, stream>>>(scanned, blockoff, offs);
    fill_k<<<nbEdge, 256, 0, stream>>>(src, dst, offs, cursor, esrc);
    aggregate_k<<<nbNode4, 256, 0, stream>>>(e_emb, b_tan, s_nrm, offs, esrc, out);
    gemm_act_k<<<dim3(nbTile, 3), 256, 0, stream>>>(out, W_e, b_e, W_b, b_b, W_s, b_s, deg);
}

// Round 2
// 749.240 us; speedup vs baseline: 1.2017x; 1.2017x over previous
//
#include <hip/hip_runtime.h>
#include <math.h>

#define N_NODESC 100000
#define N_EDGESC 1600000
#define DIMC 128
#define EPSV 1e-12f

// ---- bf16 helpers (round-to-nearest-even), packed 2 per uint ----
__device__ inline unsigned bf16r(float f) {
    unsigned u = __float_as_uint(f);
    return (u + 0x7FFFu + ((u >> 16) & 1u)) >> 16;
}
__device__ inline unsigned pack2(float lo, float hi) {
    return bf16r(lo) | (bf16r(hi) << 16);
}
__device__ inline float unlo(unsigned u) { return __uint_as_float(u << 16); }
__device__ inline float unhi(unsigned u) { return __uint_as_float(u & 0xFFFF0000u); }

// ---------------- per-node pretransform -> interleaved bf16 gather table.
// tab[node] is 192 uints (768 B): entry [lane*3 + c] = bf16x2 of dims (2*lane, 2*lane+1)
// for channel c in {e, b_tan, s_nrm}.
__global__ void pretransform_k(const float* __restrict__ e_emb,
                               const float* __restrict__ b_emb,
                               const float* __restrict__ s_emb,
                               unsigned* __restrict__ tab) {
    int wave = (blockIdx.x * blockDim.x + threadIdx.x) >> 6;
    int lane = threadIdx.x & 63;
    if (wave >= N_NODESC) return;
    float2 ev = ((const float2*)(e_emb + (size_t)wave * DIMC))[lane];
    float2 bv = ((const float2*)(b_emb + (size_t)wave * DIMC))[lane];
    float2 sv = ((const float2*)(s_emb + (size_t)wave * DIMC))[lane];
    float bss = bv.x * bv.x + bv.y * bv.y;
    float sss = sv.x * sv.x + sv.y * sv.y;
    #pragma unroll
    for (int m = 1; m < 64; m <<= 1) {
        bss += __shfl_xor(bss, m, 64);
        sss += __shfl_xor(sss, m, 64);
    }
    float bn  = sqrtf(bss);
    float bns = fmaxf(bn, EPSV);
    float bcl = fminf(fmaxf(bns, EPSV), 1.0f - 1e-5f);
    float bsc = atanhf(bcl) / bns;
    float sn  = sqrtf(sss);
    float ssc = 1.0f / fmaxf(sn, EPSV);
    unsigned* p = tab + (size_t)wave * 192 + lane * 3;
    uint3 v;
    v.x = pack2(ev.x, ev.y);
    v.y = pack2(bv.x * bsc, bv.y * bsc);
    v.z = pack2(sv.x * ssc, sv.y * ssc);
    *(uint3*)p = v;
}

// ---------------- CSR build: histogram, two-level scan, fill
__global__ void hist_k(const int* __restrict__ dst, int* __restrict__ deg) {
    int e = blockIdx.x * 256 + threadIdx.x;
    if (e < N_EDGESC) atomicAdd(&deg[dst[e]], 1);
}

__global__ void scan1_k(const int* __restrict__ deg, int* __restrict__ scanned,
                        int* __restrict__ partials) {
    __shared__ int s[256];
    int t = threadIdx.x;
    int g = blockIdx.x * 256 + t;
    int v = (g < N_NODESC) ? deg[g] : 0;
    s[t] = v;
    __syncthreads();
    for (int off = 1; off < 256; off <<= 1) {
        int x = (t >= off) ? s[t - off] : 0;
        __syncthreads();
        s[t] += x;
        __syncthreads();
    }
    if (g < N_NODESC) scanned[g] = s[t];
    if (t == 255) partials[blockIdx.x] = s[255];
}

__global__ void scan2_k(const int* __restrict__ partials, int* __restrict__ blockoff, int nb) {
    __shared__ int s[512];
    int t = threadIdx.x;
    int v = (t < nb) ? partials[t] : 0;
    s[t] = v;
    __syncthreads();
    for (int off = 1; off < 512; off <<= 1) {
        int x = (t >= off) ? s[t - off] : 0;
        __syncthreads();
        s[t] += x;
        __syncthreads();
    }
    if (t < nb) blockoff[t] = s[t] - v;  // exclusive
}

__global__ void scan3_k(const int* __restrict__ scanned, const int* __restrict__ blockoff,
                        int* __restrict__ offs) {
    int g = blockIdx.x * 256 + threadIdx.x;
    if (g < N_NODESC) offs[g + 1] = scanned[g] + blockoff[blockIdx.x];
    if (g == 0) offs[0] = 0;
}

__global__ void fill_k(const int* __restrict__ src, const int* __restrict__ dst,
                       const int* __restrict__ offs, int* __restrict__ cursor,
                       int* __restrict__ esrc) {
    int e = blockIdx.x * 256 + threadIdx.x;
    if (e < N_EDGESC) {
        int d = dst[e];
        int pos = offs[d] + atomicAdd(&cursor[d], 1);
        esrc[pos] = src[e];
    }
}

// ---------------- aggregation: one wave per node, gather bf16 interleaved table.
// Per edge, lane loads one uint3 (12 B) = 2 dims x 3 channels. Accumulate fp32.
// Writes fp32 per-channel means into d_out (transformed in-place by gemm_act_k).
__global__ void aggregate_k(const unsigned* __restrict__ tab,
                            const int* __restrict__ offs,
                            const int* __restrict__ esrc,
                            float* __restrict__ out) {
    int wave = (blockIdx.x * blockDim.x + threadIdx.x) >> 6;
    int lane = threadIdx.x & 63;
    if (wave >= N_NODESC) return;
    int beg = offs[wave], end = offs[wave + 1];
    float ae0 = 0.f, ae1 = 0.f, ab0 = 0.f, ab1 = 0.f, as0 = 0.f, as1 = 0.f;
    int j = beg;
    int lo3 = lane * 3;
    for (; j + 1 < end; j += 2) {
        int s0 = esrc[j], s1 = esrc[j + 1];
        uint3 v0 = *(const uint3*)(tab + (size_t)s0 * 192 + lo3);
        uint3 v1 = *(const uint3*)(tab + (size_t)s1 * 192 + lo3);
        ae0 += unlo(v0.x); ae1 += unhi(v0.x);
        ab0 += unlo(v0.y); ab1 += unhi(v0.y);
        as0 += unlo(v0.z); as1 += unhi(v0.z);
        ae0 += unlo(v1.x); ae1 += unhi(v1.x);
        ab0 += unlo(v1.y); ab1 += unhi(v1.y);
        as0 += unlo(v1.z); as1 += unhi(v1.z);
    }
    if (j < end) {
        int s0 = esrc[j];
        uint3 v0 = *(const uint3*)(tab + (size_t)s0 * 192 + lo3);
        ae0 += unlo(v0.x); ae1 += unhi(v0.x);
        ab0 += unlo(v0.y); ab1 += unhi(v0.y);
        as0 += unlo(v0.z); as1 += unhi(v0.z);
    }
    int deg = end - beg;
    float inv = (deg > 0) ? 1.0f / (float)deg : 0.0f;
    ((float2*)(out + (size_t)wave * DIMC))[lane]                           = make_float2(ae0 * inv, ae1 * inv);
    ((float2*)(out + (size_t)(N_NODESC + wave) * DIMC))[lane]              = make_float2(ab0 * inv, ab1 * inv);
    ((float2*)(out + (size_t)(2 * (size_t)N_NODESC + wave) * DIMC))[lane]  = make_float2(as0 * inv, as1 * inv);
}

// ---------------- fused GEMM (out = act(A @ W^T + bias)) in-place on d_out.
__global__ __launch_bounds__(256) void gemm_act_k(
    float* __restrict__ out,
    const float* __restrict__ W_e, const float* __restrict__ b_e,
    const float* __restrict__ W_b, const float* __restrict__ b_b,
    const float* __restrict__ W_s, const float* __restrict__ b_s,
    const int* __restrict__ deg) {
    __shared__ float At[64][68];   // At[k][m]
    __shared__ float Wt[64][132];  // Wt[k][j]
    int c = blockIdx.y;
    const float* W    = (c == 0) ? W_e : (c == 1) ? W_b : W_s;
    const float* bias = (c == 0) ? b_e : (c == 1) ? b_b : b_s;
    float* A = out + (size_t)c * N_NODESC * DIMC;
    int m0 = blockIdx.x * 64;
    int tid = threadIdx.x;
    int tx = tid & 31;
    int ty = tid >> 5;
    float acc[8][4] = {};

    for (int h = 0; h < 2; ++h) {
        __syncthreads();
        {
            int m = tid & 63, kq = tid >> 6;
            int row = m0 + m;
            #pragma unroll
            for (int r = 0; r < 4; ++r) {
                int k0 = kq * 16 + r * 4;
                float4 v = make_float4(0.f, 0.f, 0.f, 0.f);
                if (row < N_NODESC)
                    v = *(const float4*)(A + (size_t)row * DIMC + h * 64 + k0);
                At[k0 + 0][m] = v.x; At[k0 + 1][m] = v.y;
                At[k0 + 2][m] = v.z; At[k0 + 3][m] = v.w;
            }
        }
        {
            int j = tid & 127, kh = tid >> 7;
            #pragma unroll
            for (int r = 0; r < 8; ++r) {
                int k0 = kh * 32 + r * 4;
                float4 v = *(const float4*)(W + (size_t)j * DIMC + h * 64 + k0);
                Wt[k0 + 0][j] = v.x; Wt[k0 + 1][j] = v.y;
                Wt[k0 + 2][j] = v.z; Wt[k0 + 3][j] = v.w;
            }
        }
        __syncthreads();
        #pragma unroll 4
        for (int k = 0; k < 64; ++k) {
            float4 w  = *(const float4*)&Wt[k][tx * 4];
            float4 a0 = *(const float4*)&At[k][ty * 8];
            float4 a1 = *(const float4*)&At[k][ty * 8 + 4];
            float am[8] = {a0.x, a0.y, a0.z, a0.w, a1.x, a1.y, a1.z, a1.w};
            #pragma unroll
            for (int r = 0; r < 8; ++r) {
                acc[r][0] += am[r] * w.x;
                acc[r][1] += am[r] * w.y;
                acc[r][2] += am[r] * w.z;
                acc[r][3] += am[r] * w.w;
            }
        }
    }

    float4 bv = *(const float4*)(bias + tx * 4);
    #pragma unroll
    for (int r = 0; r < 8; ++r) {
        int m = ty * 8 + r;
        int row = m0 + m;
        if (row >= N_NODESC) continue;
        float z0 = acc[r][0] + bv.x;
        float z1 = acc[r][1] + bv.y;
        float z2 = acc[r][2] + bv.z;
        float z3 = acc[r][3] + bv.w;
        float4 o;
        if (c == 0) {
            o.x = (z0 >= 0.f) ? z0 : 0.2f * z0;
            o.y = (z1 >= 0.f) ? z1 : 0.2f * z1;
            o.z = (z2 >= 0.f) ? z2 : 0.2f * z2;
            o.w = (z3 >= 0.f) ? z3 : 0.2f * z3;
        } else {
            float ss = z0 * z0 + z1 * z1 + z2 * z2 + z3 * z3;
            #pragma unroll
            for (int mm = 1; mm < 32; mm <<= 1) ss += __shfl_xor(ss, mm, 64);
            float n = sqrtf(ss);
            float scale;
            if (c == 1) {
                float nsafe = fmaxf(n, EPSV);
                scale = tanhf(nsafe) / nsafe;       // expmap0
            } else {
                scale = 1.0f / fmaxf(n, EPSV);      // l2_normalize
            }
            if (deg[row] <= 0) scale = 0.0f;
            o = make_float4(z0 * scale, z1 * scale, z2 * scale, z3 * scale);
        }
        *(float4*)(A + (size_t)row * DIMC + tx * 4) = o;
    }
}

extern "C" void kernel_launch(void* const* d_in, const int* in_sizes, int n_in,
                              void* d_out, int out_size, void* d_ws, size_t ws_size,
                              hipStream_t stream) {
    const float* e_emb = (const float*)d_in[0];
    const float* b_emb = (const float*)d_in[1];
    const float* s_emb = (const float*)d_in[2];
    const float* W_e   = (const float*)d_in[3];
    const float* b_e   = (const float*)d_in[4];
    const float* W_b   = (const float*)d_in[5];
    const float* b_b   = (const float*)d_in[6];
    const float* W_s   = (const float*)d_in[7];
    const float* b_s   = (const float*)d_in[8];
    const int*   src   = (const int*)d_in[9];
    const int*   dst   = (const int*)d_in[10];
    float* out = (float*)d_out;

    // workspace layout
    char* w = (char*)d_ws;
    unsigned* tab = (unsigned*)w; w += (size_t)N_NODESC * 192 * sizeof(unsigned);  // 76.8 MB
    int* deg      = (int*)w;   w += (size_t)N_NODESC * sizeof(int);
    int* cursor   = (int*)w;   w += (size_t)N_NODESC * sizeof(int);
    int* scanned  = (int*)w;   w += (size_t)N_NODESC * sizeof(int);
    int* partials = (int*)w;   w += 512 * sizeof(int);
    int* blockoff = (int*)w;   w += 512 * sizeof(int);
    int* offs     = (int*)w;   w += (size_t)(N_NODESC + 1) * sizeof(int);
    w = (char*)(((uintptr_t)w + 255) & ~(uintptr_t)255);
    int* esrc     = (int*)w;   w += (size_t)N_EDGESC * sizeof(int);

    const int nbScan  = (N_NODESC + 255) / 256;   // 391
    const int nbEdge  = (N_EDGESC + 255) / 256;   // 6250
    const int nbNode4 = (N_NODESC + 3) / 4;       // 25000
    const int nbTile  = (N_NODESC + 63) / 64;     // 1563

    hipMemsetAsync(deg, 0, (size_t)2 * N_NODESC * sizeof(int), stream);

    pretransform_k<<<nbNode4, 256, 0, stream>>>(e_emb, b_emb, s_emb, tab);
    hist_k<<<nbEdge, 256, 0, stream>>>(dst, deg);
    scan1_k<<<nbScan, 256, 0, stream>>>(deg, scanned, partials);
    scan2_k<<<1, 512, 0, stream>>>(partials, blockoff, nbScan);
    scan3_k<<<nbScan, 256, 0, stream>>>(scanned, blockoff, offs);
    fill_k<<<nbEdge, 256, 0, stream>>>(src, dst, offs, cursor, esrc);
    aggregate_k<<<nbNode4, 256, 0, stream>>>(tab, offs, esrc, out);
    gemm_act_k<<<dim3(nbTile, 3), 256, 0, stream>>>(out, W_e, b_e, W_b, b_b, W_s, b_s, deg);
}